// Round 8
// baseline (227.093 us; speedup 1.0000x reference)
//
#include <hip/hip_runtime.h>
#include <hip/hip_cooperative_groups.h>
#include <stdint.h>

namespace cg = cooperative_groups;

#define MROWS 131072
#define NSPEC 8
#define DIN   128
#define NOUT  256
#define BM    32

typedef __attribute__((ext_vector_type(8))) short s16x8;
typedef __attribute__((ext_vector_type(4))) float f32x4;

// workspace layout
#define OFF_BF    ((size_t)0)        // 8*16*4*1024 = 524288 B : W in bf16, fragment order
#define OFF_PERM  ((size_t)524288)   // M*4 = 524288 B : row permutation (sorted by species)
#define OFF_META  ((size_t)1048576)  // ints: counts[8], cursors[8]
#define WS_NEEDED ((size_t)(1048576 + 256))

#define NCONV 128                    // convert work units (512 chunks / 4 per block... 32768 thr)
#define NHIST (MROWS / 256)          // 512
#define NSCAT (MROWS / 256)          // 512

__device__ __forceinline__ uint32_t bf16_bits(uint32_t u) {
  return (u + 0x7FFFu + ((u >> 16) & 1u)) >> 16;   // RNE, inputs finite
}
__device__ __forceinline__ uint32_t bf16_1(float f) {
  union { float f; uint32_t u; } v; v.f = f;
  return bf16_bits(v.u);
}

// ---------------- fused cooperative kernel: zero -> convert+hist -> scatter -> gemm
__global__ __launch_bounds__(256, 4) void k_fused(const float* __restrict__ A,
                                                  const int* __restrict__ sp,
                                                  const float* __restrict__ B,
                                                  float* __restrict__ out,
                                                  char* __restrict__ ws) {
  cg::grid_group grid = cg::this_grid();
  int* meta = (int*)(ws + OFF_META);            // counts[8], curs[8]
  int* perm = (int*)(ws + OFF_PERM);
  const char* Bf = ws + OFF_BF;
  int t = threadIdx.x;

  __shared__ char As[BM * 256];                 // gemm A-tile; aliased as bins/lbin in ph1/2
  __shared__ int prow[BM];

  // ---- phase 0: zero counts+cursors
  if (blockIdx.x == 0 && t < 16) meta[t] = 0;
  grid.sync();

  // ---- phase 1: convert W -> bf16 frag order (units 0..127) + histogram (units 128..639)
  for (int u = blockIdx.x; u < NCONV + NHIST; u += gridDim.x) {
    if (u < NCONV) {
      int gid = u * 256 + t;
      int l  = gid & 63;
      int c  = gid >> 6;                        // 0..511
      int kt = c & 3;
      int f  = (c >> 2) & 15;
      int s  = c >> 6;
      int n  = f * 16 + (l & 15);
      int k0 = kt * 32 + (l >> 4) * 8;
      const float* src = B + (size_t)s * DIN * NOUT + n;
      uint32_t w0 = bf16_1(src[(size_t)(k0 + 0) * NOUT]) | (bf16_1(src[(size_t)(k0 + 1) * NOUT]) << 16);
      uint32_t w1 = bf16_1(src[(size_t)(k0 + 2) * NOUT]) | (bf16_1(src[(size_t)(k0 + 3) * NOUT]) << 16);
      uint32_t w2 = bf16_1(src[(size_t)(k0 + 4) * NOUT]) | (bf16_1(src[(size_t)(k0 + 5) * NOUT]) << 16);
      uint32_t w3 = bf16_1(src[(size_t)(k0 + 6) * NOUT]) | (bf16_1(src[(size_t)(k0 + 7) * NOUT]) << 16);
      *(uint4*)(ws + OFF_BF + (size_t)c * 1024 + (size_t)l * 16) = make_uint4(w0, w1, w2, w3);
    } else {
      int* bins = (int*)As;
      if (t < 8) bins[t] = 0;
      __syncthreads();
      atomicAdd(&bins[sp[(u - NCONV) * 256 + t] & 7], 1);
      __syncthreads();
      if (t < 8) atomicAdd(&meta[t], bins[t]);
      __syncthreads();
    }
  }
  grid.sync();

  // ---- phase 2: scatter rows -> perm (sorted by species)
  for (int u = blockIdx.x; u < NSCAT; u += gridDim.x) {
    int* lbin  = (int*)As;
    int* gbase = lbin + 8;
    if (t < 8) lbin[t] = 0;
    __syncthreads();
    int i = u * 256 + t;
    int s = sp[i] & 7;
    int rank = atomicAdd(&lbin[s], 1);
    __syncthreads();
    if (t < 8) {
      int base = 0;
      #pragma unroll
      for (int j = 0; j < 8; ++j) base += (j < t) ? meta[j] : 0;
      gbase[t] = base + atomicAdd(&meta[8 + t], lbin[t]);
    }
    __syncthreads();
    perm[gbase[s] + rank] = i;
    __syncthreads();
  }
  grid.sync();

  // ---- phase 3: grouped GEMM, grid-stride over tiles of BM rows x 256 cols
  // tile count = sum over species of ceil(count/BM) <= 4096+7
  int totalTiles;
  {
    int toff = 0;
    #pragma unroll
    for (int j = 0; j < 8; ++j) toff += (meta[j] + BM - 1) >> 5;
    totalTiles = toff;
  }
  int w = t >> 6, l = t & 63;
  for (int bt = blockIdx.x; bt < totalTiles; bt += gridDim.x) {
    __syncthreads();                            // protect As/prow reuse across tiles
    // locate (species, tile) by register scan of counts
    int s = -1, rowStart = 0, nrows = 0;
    {
      int base = 0, toff = 0;
      #pragma unroll
      for (int j = 0; j < 8; ++j) {
        int c = meta[j];
        int nt = (c + BM - 1) >> 5;
        if (s < 0 && bt < toff + nt) {
          s = j;
          int i = bt - toff;
          rowStart = base + i * BM;
          nrows = c - i * BM; if (nrows > BM) nrows = BM;
        }
        base += c; toff += nt;
      }
    }

    // perm entries for this thread's stage rows -> registers
    int rud[4];
    #pragma unroll
    for (int it = 0; it < 4; ++it) {
      int r = (t >> 5) + it * 8;
      rud[it] = (r < nrows) ? perm[rowStart + r] : -1;
    }
    if (t < BM) prow[t] = (t < nrows) ? perm[rowStart + t] : -1;

    // stage A: fp32 -> bf16 into LDS, XOR-swizzled
    int f4 = t & 31;
    #pragma unroll
    for (int it = 0; it < 4; ++it) {
      int r = (t >> 5) + it * 8;
      int rid = rud[it];
      float4 v = make_float4(0.f, 0.f, 0.f, 0.f);
      if (rid >= 0) v = *(const float4*)(A + (size_t)rid * DIN + f4 * 4);
      uint32_t lo = bf16_1(v.x) | (bf16_1(v.y) << 16);
      uint32_t hi = bf16_1(v.z) | (bf16_1(v.w) << 16);
      int off = (r * 256 + f4 * 8) ^ ((r & 7) << 4);
      *(uint2*)(As + off) = make_uint2(lo, hi);
    }
    __syncthreads();

    f32x4 acc[2][4];
    #pragma unroll
    for (int mi = 0; mi < 2; ++mi)
      #pragma unroll
      for (int ni = 0; ni < 4; ++ni)
        acc[mi][ni] = (f32x4){0.f, 0.f, 0.f, 0.f};

    #pragma unroll
    for (int kt = 0; kt < 4; ++kt) {
      s16x8 afr[2];
      #pragma unroll
      for (int mi = 0; mi < 2; ++mi) {
        int r = mi * 16 + (l & 15);
        int off = (r * 256 + kt * 64 + (l >> 4) * 16) ^ ((r & 7) << 4);
        afr[mi] = *(const s16x8*)(As + off);
      }
      #pragma unroll
      for (int ni = 0; ni < 4; ++ni) {
        int c = (s * 16 + (w * 4 + ni)) * 4 + kt;
        s16x8 bfr = *(const s16x8*)(Bf + (size_t)c * 1024 + (size_t)l * 16);
        #pragma unroll
        for (int mi = 0; mi < 2; ++mi)
          acc[mi][ni] = __builtin_amdgcn_mfma_f32_16x16x32_bf16(afr[mi], bfr, acc[mi][ni], 0, 0, 0);
      }
    }

    // epilogue: D row = (l>>4)*4+q (+mi*16), col = l&15 (+ni*16+w*64)
    int colBase = w * 64 + (l & 15);
    #pragma unroll
    for (int mi = 0; mi < 2; ++mi) {
      #pragma unroll
      for (int q = 0; q < 4; ++q) {
        int r = mi * 16 + ((l >> 4) << 2) + q;
        int rid = prow[r];
        if (rid >= 0) {
          #pragma unroll
          for (int ni = 0; ni < 4; ++ni)
            out[(size_t)rid * NOUT + colBase + ni * 16] = acc[mi][ni][q];
        }
      }
    }
  }
}

// ---------------- fallback path (non-cooperative): R7 4-dispatch pipeline
__global__ void k_convert_hist(const float* __restrict__ B, const int* __restrict__ sp,
                               char* __restrict__ ws) {
  int blk = blockIdx.x;
  int t = threadIdx.x;
  if (blk < 128) {
    int gid = blk * 256 + t;
    int l  = gid & 63;
    int c  = gid >> 6;
    int kt = c & 3;
    int f  = (c >> 2) & 15;
    int s  = c >> 6;
    int n  = f * 16 + (l & 15);
    int k0 = kt * 32 + (l >> 4) * 8;
    const float* src = B + (size_t)s * DIN * NOUT + n;
    uint32_t w0 = bf16_1(src[(size_t)(k0 + 0) * NOUT]) | (bf16_1(src[(size_t)(k0 + 1) * NOUT]) << 16);
    uint32_t w1 = bf16_1(src[(size_t)(k0 + 2) * NOUT]) | (bf16_1(src[(size_t)(k0 + 3) * NOUT]) << 16);
    uint32_t w2 = bf16_1(src[(size_t)(k0 + 4) * NOUT]) | (bf16_1(src[(size_t)(k0 + 5) * NOUT]) << 16);
    uint32_t w3 = bf16_1(src[(size_t)(k0 + 6) * NOUT]) | (bf16_1(src[(size_t)(k0 + 7) * NOUT]) << 16);
    *(uint4*)(ws + OFF_BF + (size_t)c * 1024 + (size_t)l * 16) = make_uint4(w0, w1, w2, w3);
  } else {
    __shared__ int bins[8];
    int* counts = (int*)(ws + OFF_META);
    if (t < 8) bins[t] = 0;
    __syncthreads();
    atomicAdd(&bins[sp[(blk - 128) * 256 + t] & 7], 1);
    __syncthreads();
    if (t < 8) atomicAdd(&counts[t], bins[t]);
  }
}

__global__ void k_scatter(const int* __restrict__ sp, char* __restrict__ ws) {
  __shared__ int lbin[8], gbase[8];
  int* counts = (int*)(ws + OFF_META);
  int* curs   = counts + 8;
  int* perm   = (int*)(ws + OFF_PERM);
  int t = threadIdx.x;
  if (t < 8) lbin[t] = 0;
  __syncthreads();
  int i = blockIdx.x * 256 + t;
  int s = sp[i] & 7;
  int rank = atomicAdd(&lbin[s], 1);
  __syncthreads();
  if (t < 8) {
    int base = 0;
    #pragma unroll
    for (int j = 0; j < 8; ++j) base += (j < t) ? counts[j] : 0;
    gbase[t] = base + atomicAdd(&curs[t], lbin[t]);
  }
  __syncthreads();
  perm[gbase[s] + rank] = i;
}

__global__ __launch_bounds__(256, 5) void k_gemm(const float* __restrict__ A,
                                                 const char* __restrict__ ws,
                                                 float* __restrict__ out) {
  const int* counts = (const int*)(ws + OFF_META);
  const int* perm   = (const int*)(ws + OFF_PERM);
  const char* Bf    = ws + OFF_BF;
  __shared__ char As[BM * 256];
  __shared__ int prow[BM];
  int b = blockIdx.x;
  int s = -1, rowStart = 0, nrows = 0;
  {
    int base = 0, toff = 0;
    #pragma unroll
    for (int j = 0; j < 8; ++j) {
      int c = counts[j];
      int nt = (c + BM - 1) >> 5;
      if (s < 0 && b < toff + nt) {
        s = j;
        int i = b - toff;
        rowStart = base + i * BM;
        nrows = c - i * BM; if (nrows > BM) nrows = BM;
      }
      base += c; toff += nt;
    }
    if (s < 0) return;
  }
  int t = threadIdx.x;
  int rud[4];
  #pragma unroll
  for (int it = 0; it < 4; ++it) {
    int r = (t >> 5) + it * 8;
    rud[it] = (r < nrows) ? perm[rowStart + r] : -1;
  }
  if (t < BM) prow[t] = (t < nrows) ? perm[rowStart + t] : -1;
  int f4 = t & 31;
  #pragma unroll
  for (int it = 0; it < 4; ++it) {
    int r = (t >> 5) + it * 8;
    int rid = rud[it];
    float4 v = make_float4(0.f, 0.f, 0.f, 0.f);
    if (rid >= 0) v = *(const float4*)(A + (size_t)rid * DIN + f4 * 4);
    uint32_t lo = bf16_1(v.x) | (bf16_1(v.y) << 16);
    uint32_t hi = bf16_1(v.z) | (bf16_1(v.w) << 16);
    int off = (r * 256 + f4 * 8) ^ ((r & 7) << 4);
    *(uint2*)(As + off) = make_uint2(lo, hi);
  }
  __syncthreads();
  int w = t >> 6, l = t & 63;
  f32x4 acc[2][4];
  #pragma unroll
  for (int mi = 0; mi < 2; ++mi)
    #pragma unroll
    for (int ni = 0; ni < 4; ++ni)
      acc[mi][ni] = (f32x4){0.f, 0.f, 0.f, 0.f};
  #pragma unroll
  for (int kt = 0; kt < 4; ++kt) {
    s16x8 afr[2];
    #pragma unroll
    for (int mi = 0; mi < 2; ++mi) {
      int r = mi * 16 + (l & 15);
      int off = (r * 256 + kt * 64 + (l >> 4) * 16) ^ ((r & 7) << 4);
      afr[mi] = *(const s16x8*)(As + off);
    }
    #pragma unroll
    for (int ni = 0; ni < 4; ++ni) {
      int c = (s * 16 + (w * 4 + ni)) * 4 + kt;
      s16x8 bfr = *(const s16x8*)(Bf + (size_t)c * 1024 + (size_t)l * 16);
      #pragma unroll
      for (int mi = 0; mi < 2; ++mi)
        acc[mi][ni] = __builtin_amdgcn_mfma_f32_16x16x32_bf16(afr[mi], bfr, acc[mi][ni], 0, 0, 0);
    }
  }
  int colBase = w * 64 + (l & 15);
  #pragma unroll
  for (int mi = 0; mi < 2; ++mi) {
    #pragma unroll
    for (int q = 0; q < 4; ++q) {
      int r = mi * 16 + ((l >> 4) << 2) + q;
      int rid = prow[r];
      if (rid >= 0) {
        #pragma unroll
        for (int ni = 0; ni < 4; ++ni)
          out[(size_t)rid * NOUT + colBase + ni * 16] = acc[mi][ni][q];
      }
    }
  }
}

__global__ void k_naive(const float* __restrict__ A, const int* __restrict__ sp,
                        const float* __restrict__ B, float* __restrict__ out) {
  __shared__ float av[DIN];
  int m = blockIdx.x;
  int n = threadIdx.x;
  if (n < DIN) av[n] = A[(size_t)m * DIN + n];
  __syncthreads();
  int s = sp[m] & 7;
  const float* b = B + (size_t)s * DIN * NOUT + n;
  float acc = 0.f;
  #pragma unroll 8
  for (int k = 0; k < DIN; ++k) acc = fmaf(av[k], b[(size_t)k * NOUT], acc);
  out[(size_t)m * NOUT + n] = acc;
}

extern "C" void kernel_launch(void* const* d_in, const int* in_sizes, int n_in,
                              void* d_out, int out_size, void* d_ws, size_t ws_size,
                              hipStream_t stream) {
  const float* values = (const float*)d_in[0];
  const int*   sp     = (const int*)d_in[1];
  const float* B      = (const float*)d_in[2];
  float*       out    = (float*)d_out;

  if (d_ws == nullptr || ws_size < WS_NEEDED) {
    k_naive<<<MROWS, NOUT, 0, stream>>>(values, sp, B, out);
    return;
  }
  char* wsp = (char*)d_ws;

  // host-side queries (no stream ops; graph-capture safe)
  int dev = 0;
  (void)hipGetDevice(&dev);
  int coop = 0;
  (void)hipDeviceGetAttribute(&coop, hipDeviceAttributeCooperativeLaunch, dev);
  int mbpc = 0;
  (void)hipOccupancyMaxActiveBlocksPerMultiprocessor(&mbpc, (const void*)k_fused, 256, 0);
  int ncu = 0;
  (void)hipDeviceGetAttribute(&ncu, hipDeviceAttributeMultiprocessorCount, dev);

  if (coop && mbpc > 0 && ncu > 0) {
    int nblk = mbpc * ncu;
    int maxw = MROWS / BM + NSPEC;              // enough for every phase
    if (nblk > maxw) nblk = maxw;
    void* args[5] = {(void*)&values, (void*)&sp, (void*)&B, (void*)&out, (void*)&wsp};
    (void)hipLaunchCooperativeKernel((const void*)k_fused, dim3(nblk), dim3(256),
                                     args, 0, stream);
  } else {
    (void)hipMemsetAsync(wsp + OFF_META, 0, 64, stream);
    k_convert_hist<<<128 + MROWS / 256, 256, 0, stream>>>(B, sp, wsp);
    k_scatter<<<MROWS / 256, 256, 0, stream>>>(sp, wsp);
    k_gemm<<<MROWS / BM + NSPEC, 256, 0, stream>>>(values, wsp, out);
  }
}

// Round 9
// 42.801 us; speedup vs baseline: 5.3058x; 5.3058x over previous
//
#include <hip/hip_runtime.h>
#include <stdint.h>

#define MROWS 131072
#define NSPEC 8
#define DIN   128
#define NOUT  256
#define BM    256                    // natural rows per block (block-local sort)

typedef __attribute__((ext_vector_type(8))) short s16x8;
typedef __attribute__((ext_vector_type(4))) float f32x4;

// workspace: only the bf16 fragment-ordered W
#define OFF_BF    ((size_t)0)        // 8*16*4*1024 = 524288 B
#define WS_NEEDED ((size_t)524288)

__device__ __forceinline__ uint32_t bf16_1(float f) {
  union { float f; uint32_t u; } v; v.f = f;
  return (v.u + 0x7FFFu + ((v.u >> 16) & 1u)) >> 16;  // RNE, inputs finite
}

// Convert W [8][128][256] fp32 -> bf16 fragment order (as before):
// chunk c = ((s*16 + nfrag)*4 + kt); lane l holds
// B[k = kt*32 + (l>>4)*8 + j][n = nfrag*16 + (l&15)], j=0..7 (16B contiguous).
__global__ void k_convert(const float* __restrict__ B, char* __restrict__ ws) {
  int gid = blockIdx.x * 256 + threadIdx.x;   // 32768 threads
  int l  = gid & 63;
  int c  = gid >> 6;                          // 0..511
  int kt = c & 3;
  int f  = (c >> 2) & 15;
  int s  = c >> 6;
  int n  = f * 16 + (l & 15);
  int k0 = kt * 32 + (l >> 4) * 8;
  const float* src = B + (size_t)s * DIN * NOUT + n;
  uint32_t w0 = bf16_1(src[(size_t)(k0 + 0) * NOUT]) | (bf16_1(src[(size_t)(k0 + 1) * NOUT]) << 16);
  uint32_t w1 = bf16_1(src[(size_t)(k0 + 2) * NOUT]) | (bf16_1(src[(size_t)(k0 + 3) * NOUT]) << 16);
  uint32_t w2 = bf16_1(src[(size_t)(k0 + 4) * NOUT]) | (bf16_1(src[(size_t)(k0 + 5) * NOUT]) << 16);
  uint32_t w3 = bf16_1(src[(size_t)(k0 + 6) * NOUT]) | (bf16_1(src[(size_t)(k0 + 7) * NOUT]) << 16);
  *(uint4*)(ws + OFF_BF + (size_t)c * 1024 + (size_t)l * 16) = make_uint4(w0, w1, w2, w3);
}

// Sort-free grouped GEMM: one block = 256 NATURAL rows x 256 cols, 4 waves.
// Block-local counting sort into LDS slots; per species: B-frags in regs,
// MFMA over the species' slot range; boundary subtiles recomputed per species
// with predicated stores (un-stored rows may compute garbage — harmless).
__global__ __launch_bounds__(256, 2) void k_gemm_ns(const float* __restrict__ A,
                                                    const int* __restrict__ sp,
                                                    const char* __restrict__ ws,
                                                    float* __restrict__ out) {
  const char* Bf = ws + OFF_BF;
  __shared__ char As[BM * 256];     // 64 KB: [slot][128 k] bf16, XOR-swizzled
  __shared__ int slotOf[BM];        // natural row (in-block) -> slot
  __shared__ int invOf[BM];         // slot -> natural row (in-block)
  __shared__ int cnt[NSPEC];
  __shared__ int gstart[NSPEC + 1];

  int t = threadIdx.x;
  int base = blockIdx.x * BM;

  // ---- block-local counting sort of 256 rows by species
  if (t < NSPEC) cnt[t] = 0;
  __syncthreads();
  int s_r = sp[base + t] & 7;                 // thread t owns natural row t
  int rank = atomicAdd(&cnt[s_r], 1);
  __syncthreads();
  if (t == 0) {
    int a = 0;
    #pragma unroll
    for (int j = 0; j < NSPEC; ++j) { gstart[j] = a; a += cnt[j]; }
    gstart[NSPEC] = a;                        // == BM
  }
  __syncthreads();
  int myslot = gstart[s_r] + rank;
  slotOf[t] = myslot;
  invOf[myslot] = t;
  __syncthreads();

  // ---- stage A: SEQUENTIAL global reads, LDS write at sorted slot
  int f4 = t & 31, r0 = t >> 5;               // 8 rows per iteration
  #pragma unroll
  for (int it = 0; it < 32; ++it) {
    int r = r0 + it * 8;
    float4 v = *(const float4*)(A + (size_t)(base + r) * DIN + f4 * 4);
    int sl = slotOf[r];                       // broadcast within 32-lane group
    uint32_t lo = bf16_1(v.x) | (bf16_1(v.y) << 16);
    uint32_t hi = bf16_1(v.z) | (bf16_1(v.w) << 16);
    int off = (sl * 256 + f4 * 8) ^ ((sl & 7) << 4);   // G4 swizzle
    *(uint2*)(As + off) = make_uint2(lo, hi);
  }
  __syncthreads();

  // ---- per-species MFMA over slot ranges
  int w = t >> 6, l = t & 63;
  int colBase = w * 64 + (l & 15);
  for (int s = 0; s < NSPEC; ++s) {
    int gs = gstart[s], ge = gstart[s + 1];
    if (gs == ge) continue;
    // B fragments for this species & this wave's 64-col strip: 16 x 1KB from L2
    s16x8 bfr[4][4];                          // [ni][kt], fully unrolled -> regs
    #pragma unroll
    for (int ni = 0; ni < 4; ++ni)
      #pragma unroll
      for (int kt = 0; kt < 4; ++kt) {
        int c = (s * 16 + (w * 4 + ni)) * 4 + kt;
        bfr[ni][kt] = *(const s16x8*)(Bf + (size_t)c * 1024 + (size_t)l * 16);
      }
    int st0 = gs >> 4, st1 = (ge - 1) >> 4;   // subtiles touching this group
    for (int st = st0; st <= st1; ++st) {
      f32x4 acc[4];
      #pragma unroll
      for (int ni = 0; ni < 4; ++ni) acc[ni] = (f32x4){0.f, 0.f, 0.f, 0.f};
      #pragma unroll
      for (int kt = 0; kt < 4; ++kt) {
        int r = st * 16 + (l & 15);
        int off = (r * 256 + kt * 64 + (l >> 4) * 16) ^ ((r & 7) << 4);
        s16x8 afr = *(const s16x8*)(As + off);
        #pragma unroll
        for (int ni = 0; ni < 4; ++ni)
          acc[ni] = __builtin_amdgcn_mfma_f32_16x16x32_bf16(afr, bfr[ni][kt], acc[ni], 0, 0, 0);
      }
      // predicated store: only rows belonging to species s
      #pragma unroll
      for (int q = 0; q < 4; ++q) {
        int slotrow = st * 16 + ((l >> 4) << 2) + q;
        if (slotrow >= gs && slotrow < ge) {
          int rid = base + invOf[slotrow];    // broadcast within 16-lane group
          #pragma unroll
          for (int ni = 0; ni < 4; ++ni)
            out[(size_t)rid * NOUT + colBase + ni * 16] = acc[ni][q];
        }
      }
    }
  }
}

// ws-free correctness fallback (only if ws_size is unexpectedly small)
__global__ void k_naive(const float* __restrict__ A, const int* __restrict__ sp,
                        const float* __restrict__ B, float* __restrict__ out) {
  __shared__ float av[DIN];
  int m = blockIdx.x;
  int n = threadIdx.x;
  if (n < DIN) av[n] = A[(size_t)m * DIN + n];
  __syncthreads();
  int s = sp[m] & 7;
  const float* b = B + (size_t)s * DIN * NOUT + n;
  float acc = 0.f;
  #pragma unroll 8
  for (int k = 0; k < DIN; ++k) acc = fmaf(av[k], b[(size_t)k * NOUT], acc);
  out[(size_t)m * NOUT + n] = acc;
}

extern "C" void kernel_launch(void* const* d_in, const int* in_sizes, int n_in,
                              void* d_out, int out_size, void* d_ws, size_t ws_size,
                              hipStream_t stream) {
  const float* values = (const float*)d_in[0];
  const int*   sp     = (const int*)d_in[1];
  const float* B      = (const float*)d_in[2];
  float*       out    = (float*)d_out;

  if (d_ws == nullptr || ws_size < WS_NEEDED) {
    k_naive<<<MROWS, NOUT, 0, stream>>>(values, sp, B, out);
    return;
  }
  char* ws = (char*)d_ws;
  k_convert<<<128, 256, 0, stream>>>(B, ws);
  k_gemm_ns<<<MROWS / BM, 256, 0, stream>>>(values, sp, ws, out);
}

// Round 10
// 42.594 us; speedup vs baseline: 5.3316x; 1.0049x over previous
//
#include <hip/hip_runtime.h>
#include <stdint.h>

#define MROWS 131072
#define NSPEC 8
#define DIN   128
#define NOUT  256
#define BM    256                    // natural rows per block (block-local sort)

typedef __attribute__((ext_vector_type(8))) short s16x8;
typedef __attribute__((ext_vector_type(4))) float f32x4;

// workspace: only the bf16 fragment-ordered W
#define OFF_BF    ((size_t)0)        // 8*16*4*1024 = 524288 B
#define WS_NEEDED ((size_t)524288)

__device__ __forceinline__ uint32_t bf16_1(float f) {
  union { float f; uint32_t u; } v; v.f = f;
  return (v.u + 0x7FFFu + ((v.u >> 16) & 1u)) >> 16;  // RNE, inputs finite
}

// Convert W [8][128][256] fp32 -> bf16 fragment order.
// chunk c = ((s*16 + f)*4 + kt); lane l holds
// B[k = kt*32 + (l>>4)*8 + j][n], j=0..7.
// COLUMN-INTERLEAVED mapping: f = w*4 + ni  ->  n = w*64 + (l&15)*4 + ni
// so that D-tile ni, lane m covers global col w*64 + m*4 + ni; a lane's four
// ni-values are then 4 CONSECUTIVE floats -> float4 epilogue stores.
__global__ void k_convert(const float* __restrict__ B, char* __restrict__ ws) {
  int gid = blockIdx.x * 256 + threadIdx.x;   // 32768 threads
  int l  = gid & 63;
  int c  = gid >> 6;                          // 0..511
  int kt = c & 3;
  int f  = (c >> 2) & 15;
  int s  = c >> 6;
  int n  = (f >> 2) * 64 + (l & 15) * 4 + (f & 3);
  int k0 = kt * 32 + (l >> 4) * 8;
  const float* src = B + (size_t)s * DIN * NOUT + n;
  uint32_t w0 = bf16_1(src[(size_t)(k0 + 0) * NOUT]) | (bf16_1(src[(size_t)(k0 + 1) * NOUT]) << 16);
  uint32_t w1 = bf16_1(src[(size_t)(k0 + 2) * NOUT]) | (bf16_1(src[(size_t)(k0 + 3) * NOUT]) << 16);
  uint32_t w2 = bf16_1(src[(size_t)(k0 + 4) * NOUT]) | (bf16_1(src[(size_t)(k0 + 5) * NOUT]) << 16);
  uint32_t w3 = bf16_1(src[(size_t)(k0 + 6) * NOUT]) | (bf16_1(src[(size_t)(k0 + 7) * NOUT]) << 16);
  *(uint4*)(ws + OFF_BF + (size_t)c * 1024 + (size_t)l * 16) = make_uint4(w0, w1, w2, w3);
}

// Sort-free grouped GEMM: one block = 256 NATURAL rows x 256 cols, 4 waves.
// Block-local counting sort into LDS slots; per species: B-frags in regs,
// MFMA over the species' slot range; boundary subtiles recomputed per species
// with predicated float4 stores.
__global__ __launch_bounds__(256, 2) void k_gemm_ns(const float* __restrict__ A,
                                                    const int* __restrict__ sp,
                                                    const char* __restrict__ ws,
                                                    float* __restrict__ out) {
  const char* Bf = ws + OFF_BF;
  __shared__ char As[BM * 256];     // 64 KB: [slot][128 k] bf16, XOR-swizzled
  __shared__ int slotOf[BM];        // natural row (in-block) -> slot
  __shared__ int invOf[BM];         // slot -> natural row (in-block)
  __shared__ int cnt[NSPEC];
  __shared__ int gstart[NSPEC + 1];

  int t = threadIdx.x;
  int base = blockIdx.x * BM;

  // ---- block-local counting sort of 256 rows by species
  if (t < NSPEC) cnt[t] = 0;
  __syncthreads();
  int s_r = sp[base + t] & 7;                 // thread t owns natural row t
  int rank = atomicAdd(&cnt[s_r], 1);
  __syncthreads();
  if (t == 0) {
    int a = 0;
    #pragma unroll
    for (int j = 0; j < NSPEC; ++j) { gstart[j] = a; a += cnt[j]; }
    gstart[NSPEC] = a;                        // == BM
  }
  __syncthreads();
  int myslot = gstart[s_r] + rank;
  slotOf[t] = myslot;
  invOf[myslot] = t;
  __syncthreads();

  // ---- stage A: SEQUENTIAL global reads, LDS write at sorted slot
  int f4 = t & 31, r0 = t >> 5;               // 8 rows per iteration
  #pragma unroll
  for (int it = 0; it < 32; ++it) {
    int r = r0 + it * 8;
    float4 v = *(const float4*)(A + (size_t)(base + r) * DIN + f4 * 4);
    int sl = slotOf[r];                       // broadcast within 32-lane group
    uint32_t lo = bf16_1(v.x) | (bf16_1(v.y) << 16);
    uint32_t hi = bf16_1(v.z) | (bf16_1(v.w) << 16);
    int off = (sl * 256 + f4 * 8) ^ ((sl & 7) << 4);   // G4 swizzle
    *(uint2*)(As + off) = make_uint2(lo, hi);
  }
  __syncthreads();

  // ---- per-species MFMA over slot ranges
  int w = t >> 6, l = t & 63;
  int colBase = w * 64 + (l & 15) * 4;        // col-interleaved layout
  for (int s = 0; s < NSPEC; ++s) {
    int gs = gstart[s], ge = gstart[s + 1];
    if (gs == ge) continue;
    // B fragments for this species & this wave's 64-col strip: 16 x 1KB from L2
    s16x8 bfr[4][4];                          // [ni][kt], fully unrolled -> regs
    #pragma unroll
    for (int ni = 0; ni < 4; ++ni)
      #pragma unroll
      for (int kt = 0; kt < 4; ++kt) {
        int c = (s * 16 + (w * 4 + ni)) * 4 + kt;
        bfr[ni][kt] = *(const s16x8*)(Bf + (size_t)c * 1024 + (size_t)l * 16);
      }
    int st0 = gs >> 4, st1 = (ge - 1) >> 4;   // subtiles touching this group
    for (int st = st0; st <= st1; ++st) {
      f32x4 acc[4];
      #pragma unroll
      for (int ni = 0; ni < 4; ++ni) acc[ni] = (f32x4){0.f, 0.f, 0.f, 0.f};
      #pragma unroll
      for (int kt = 0; kt < 4; ++kt) {
        int r = st * 16 + (l & 15);
        int off = (r * 256 + kt * 64 + (l >> 4) * 16) ^ ((r & 7) << 4);
        s16x8 afr = *(const s16x8*)(As + off);
        #pragma unroll
        for (int ni = 0; ni < 4; ++ni)
          acc[ni] = __builtin_amdgcn_mfma_f32_16x16x32_bf16(afr, bfr[ni][kt], acc[ni], 0, 0, 0);
      }
      // predicated float4 store: lane's 4 ni-values are consecutive cols
      #pragma unroll
      for (int q = 0; q < 4; ++q) {
        int slotrow = st * 16 + ((l >> 4) << 2) + q;
        if (slotrow >= gs && slotrow < ge) {
          int rid = base + invOf[slotrow];    // broadcast within 16-lane group
          float4 v4 = make_float4(acc[0][q], acc[1][q], acc[2][q], acc[3][q]);
          *(float4*)(out + (size_t)rid * NOUT + colBase) = v4;
        }
      }
    }
  }
}

// ws-free correctness fallback (only if ws_size is unexpectedly small)
__global__ void k_naive(const float* __restrict__ A, const int* __restrict__ sp,
                        const float* __restrict__ B, float* __restrict__ out) {
  __shared__ float av[DIN];
  int m = blockIdx.x;
  int n = threadIdx.x;
  if (n < DIN) av[n] = A[(size_t)m * DIN + n];
  __syncthreads();
  int s = sp[m] & 7;
  const float* b = B + (size_t)s * DIN * NOUT + n;
  float acc = 0.f;
  #pragma unroll 8
  for (int k = 0; k < DIN; ++k) acc = fmaf(av[k], b[(size_t)k * NOUT], acc);
  out[(size_t)m * NOUT + n] = acc;
}

extern "C" void kernel_launch(void* const* d_in, const int* in_sizes, int n_in,
                              void* d_out, int out_size, void* d_ws, size_t ws_size,
                              hipStream_t stream) {
  const float* values = (const float*)d_in[0];
  const int*   sp     = (const int*)d_in[1];
  const float* B      = (const float*)d_in[2];
  float*       out    = (float*)d_out;

  if (d_ws == nullptr || ws_size < WS_NEEDED) {
    k_naive<<<MROWS, NOUT, 0, stream>>>(values, sp, B, out);
    return;
  }
  char* ws = (char*)d_ws;
  k_convert<<<128, 256, 0, stream>>>(B, ws);
  k_gemm_ns<<<MROWS / BM, 256, 0, stream>>>(values, sp, ws, out);
}